// Round 1
// baseline (4855.318 us; speedup 1.0000x reference)
//
#include <hip/hip_runtime.h>
#include <math.h>

// Problem constants (from setup_inputs): B=32, T=64, I=E=Ha=Hb=256, O=1, P=T-1=63
#define B_   32
#define T_   64
#define P_   63
#define E_   256
#define H_   256
#define G3_  768
#define TRI_ 2016   // sum_{p=0}^{62} (p+1)

__device__ __forceinline__ float sigmoidf_(float x) { return 1.0f / (1.0f + __expf(-x)); }

// ---------------------------------------------------------------- K0: M[e,i] = out_w0[e]*emb_w[e,i]
__global__ __launch_bounds__(256) void k_prep(const float* __restrict__ emb_w,
                                              const float* __restrict__ out_w,
                                              float* __restrict__ Mmat) {
    int e = blockIdx.x, i = threadIdx.x;
    Mmat[(size_t)e * 256 + i] = out_w[e] * emb_w[(size_t)e * 256 + i];
}

// ---------------------------------------------------------------- K1: emb[t,b,e] = emb_w @ x[b,t,:] + emb_b
__global__ __launch_bounds__(256) void k_emb(const float* __restrict__ x,
                                             const float* __restrict__ emb_w,
                                             const float* __restrict__ emb_b,
                                             float* __restrict__ emb) {
    int t = blockIdx.x >> 5, b = blockIdx.x & 31;
    int tid = threadIdx.x;
    __shared__ float xr[E_];
    xr[tid] = x[((size_t)b * T_ + t) * E_ + tid];
    __syncthreads();
    const float* wr = emb_w + (size_t)tid * E_;
    float acc = emb_b[tid];
    for (int c = 0; c < 256; c += 4) {
        float4 wv = *reinterpret_cast<const float4*>(wr + c);
        float4 xv = *reinterpret_cast<const float4*>(&xr[c]);
        acc += wv.x * xv.x + wv.y * xv.y + wv.z * xv.z + wv.w * xv.w;
    }
    emb[((size_t)t * B_ + b) * E_ + tid] = acc;
}

// ---------------------------------------------------------------- K2: input gates gi{a,b}[tb, 768] = emb[tb] @ w_ih^T + b_ih
// 256 blocks x 8 rows: weights amortized over 8 (t,b) rows.
__global__ __launch_bounds__(256) void k_gates(const float* __restrict__ emb,
                                               const float* __restrict__ awih, const float* __restrict__ abih,
                                               const float* __restrict__ bwih, const float* __restrict__ bbih,
                                               float* __restrict__ gia, float* __restrict__ gib) {
    int r0 = blockIdx.x * 8;
    int tid = threadIdx.x;
    __shared__ float es[8][E_];
    for (int rr = 0; rr < 8; ++rr) es[rr][tid] = emb[(size_t)(r0 + rr) * E_ + tid];
    __syncthreads();
    for (int gs = 0; gs < 6; ++gs) {
        const float* W    = (gs < 3) ? awih : bwih;
        const float* bias = (gs < 3) ? abih : bbih;
        float* out        = (gs < 3) ? gia  : gib;
        int grow = (gs % 3) * 256 + tid;
        const float* wr = W + (size_t)grow * E_;
        float acc[8];
        #pragma unroll
        for (int rr = 0; rr < 8; ++rr) acc[rr] = 0.f;
        for (int c = 0; c < 256; c += 4) {
            float4 wv = *reinterpret_cast<const float4*>(wr + c);
            #pragma unroll
            for (int rr = 0; rr < 8; ++rr) {
                float4 ev = *reinterpret_cast<const float4*>(&es[rr][c]);
                acc[rr] += wv.x * ev.x + wv.y * ev.y + wv.z * ev.z + wv.w * ev.w;
            }
        }
        float bv = bias[grow];
        #pragma unroll
        for (int rr = 0; rr < 8; ++rr) out[(size_t)(r0 + rr) * G3_ + grow] = acc[rr] + bv;
    }
}

// ---------------------------------------------------------------- K3: triangular GRU chains
// block = (gru g, prefix p, batch-quarter q): 2*63*4 = 504 blocks. 8 batch rows per block.
// Step k of prefix p consumes input gates gi[p-k, b]; state after step k is ha/hb[p, k].
// GRU a: compute pre[p, p-k, b] = 0.5*dot(h_new, alpha_w) + alpha_b inline (no state store).
// GRU b: store every state into hstore row (p(p+1)/2 + k).
__global__ __launch_bounds__(256) void k_gru(const float* __restrict__ gia, const float* __restrict__ gib,
                                             const float* __restrict__ awhh, const float* __restrict__ abhh,
                                             const float* __restrict__ bwhh, const float* __restrict__ bbhh,
                                             const float* __restrict__ alpha_w, const float* __restrict__ alpha_b,
                                             float* __restrict__ pre, float* __restrict__ hstore) {
    int g   = blockIdx.x / 252;
    int rem = blockIdx.x % 252;
    int p   = 62 - (rem >> 2);     // large p first (critical path starts early)
    int q   = rem & 3;
    int tid = threadIdx.x;
    const float* gi  = g ? gib  : gia;
    const float* whh = g ? bwhh : awhh;
    const float* bhh = g ? bbhh : abhh;
    __shared__ float hs[8][H_];
    __shared__ float red[4][8];
    #pragma unroll
    for (int r = 0; r < 8; ++r) hs[r][tid] = 0.f;
    __syncthreads();
    float bh0 = bhh[tid], bh1 = bhh[tid + 256], bh2 = bhh[tid + 512];
    float aw = alpha_w[tid];
    float ab = alpha_b[0];
    const float* w0 = whh + (size_t)tid * 256;
    const float* w1 = w0 + 256u * 256u;
    const float* w2 = w1 + 256u * 256u;
    size_t tri = (size_t)p * (p + 1) / 2;
    for (int k = 0; k <= p; ++k) {
        int t_in = p - k;
        float a0[8], a1[8], a2[8];
        #pragma unroll
        for (int r = 0; r < 8; ++r) { a0[r] = 0.f; a1[r] = 0.f; a2[r] = 0.f; }
        for (int c = 0; c < 256; c += 4) {
            float4 wv0 = *reinterpret_cast<const float4*>(w0 + c);
            float4 wv1 = *reinterpret_cast<const float4*>(w1 + c);
            float4 wv2 = *reinterpret_cast<const float4*>(w2 + c);
            #pragma unroll
            for (int r = 0; r < 8; ++r) {
                float4 hv = *reinterpret_cast<const float4*>(&hs[r][c]);
                a0[r] += wv0.x * hv.x + wv0.y * hv.y + wv0.z * hv.z + wv0.w * hv.w;
                a1[r] += wv1.x * hv.x + wv1.y * hv.y + wv1.z * hv.z + wv1.w * hv.w;
                a2[r] += wv2.x * hv.x + wv2.y * hv.y + wv2.z * hv.z + wv2.w * hv.w;
            }
        }
        __syncthreads();   // all reads of hs done
        float part[8];
        #pragma unroll
        for (int r = 0; r < 8; ++r) {
            int b = q * 8 + r;
            const float* gr = gi + ((size_t)t_in * B_ + b) * G3_;
            float xr = gr[tid], xz = gr[tid + 256], xn = gr[tid + 512];
            float rr = sigmoidf_(xr + a0[r] + bh0);
            float zz = sigmoidf_(xz + a1[r] + bh1);
            float nn = tanhf(xn + rr * (a2[r] + bh2));
            float hold = hs[r][tid];
            float hnew = (1.f - zz) * nn + zz * hold;
            hs[r][tid] = hnew;
            if (g) {
                hstore[((tri + (size_t)k) * B_ + b) * (size_t)H_ + tid] = hnew;
                part[r] = 0.f;
            } else {
                part[r] = hnew * aw;
            }
        }
        if (!g) {
            #pragma unroll
            for (int r = 0; r < 8; ++r) {
                float v = part[r];
                #pragma unroll
                for (int off = 32; off > 0; off >>= 1) v += __shfl_down(v, off, 64);
                if ((tid & 63) == 0) red[tid >> 6][r] = v;
            }
            __syncthreads();   // hs + red visible
            if (tid < 8) {
                float s = red[0][tid] + red[1][tid] + red[2][tid] + red[3][tid];
                pre[((size_t)p * T_ + t_in) * B_ + (q * 8 + tid)] = 0.5f * s + ab;
            }
            // no extra sync needed: next iteration's first sync orders red rewrite
        } else {
            __syncthreads();   // hs writes visible before next step's reads
        }
    }
}

// ---------------------------------------------------------------- K4: softmax over k<=p per (p,b)
__global__ __launch_bounds__(64) void k_softmax(const float* __restrict__ pre, float* __restrict__ alpha) {
    int p = blockIdx.x >> 5, b = blockIdx.x & 31;
    int k = threadIdx.x;
    float v = (k <= p) ? pre[((size_t)p * T_ + k) * B_ + b] : -3.4e38f;
    float m = v;
    #pragma unroll
    for (int off = 32; off > 0; off >>= 1) m = fmaxf(m, __shfl_xor(m, off, 64));
    float e = (k <= p) ? __expf(v - m) : 0.f;
    float s = e;
    #pragma unroll
    for (int off = 32; off > 0; off >>= 1) s += __shfl_xor(s, off, 64);
    if (k <= p) alpha[((size_t)p * T_ + k) * B_ + b] = e / s;
}

// ---------------------------------------------------------------- K5a: U = alpha * tanh(0.5*H @ beta_w^T + beta_b), in-place over hstore;
// also context c and pred. block=(p,b), thread=e, k in register chunks of 16.
__global__ __launch_bounds__(256) void k_beta(float* __restrict__ hstore,   // in: states, out: U (in-place, disjoint per block)
                                              const float* __restrict__ beta_w, const float* __restrict__ beta_b,
                                              const float* __restrict__ alpha,
                                              const float* __restrict__ emb,
                                              const float* __restrict__ out_w, const float* __restrict__ out_b,
                                              float* __restrict__ outp) {
    int p = 62 - (blockIdx.x >> 5);
    int b = blockIdx.x & 31;
    int tid = threadIdx.x;
    __shared__ float Hs[64][E_];   // 64 KB
    size_t tri = (size_t)p * (p + 1) / 2;
    for (int k = 0; k <= p; ++k)   // Hs[k] = 0.5 * state after step (p-k)  (= fb for attention pos k)
        Hs[k][tid] = 0.5f * hstore[((tri + (size_t)(p - k)) * B_ + b) * (size_t)E_ + tid];
    __syncthreads();
    const float* wr = beta_w + (size_t)tid * E_;
    float bb = beta_b[tid];
    float cacc = 0.f;
    int nch = (p >> 4) + 1;
    for (int kc = 0; kc < nch; ++kc) {
        float acc[16];
        #pragma unroll
        for (int kk = 0; kk < 16; ++kk) acc[kk] = 0.f;
        for (int c = 0; c < 256; c += 4) {
            float4 wv = *reinterpret_cast<const float4*>(wr + c);
            #pragma unroll
            for (int kk = 0; kk < 16; ++kk) {
                float4 hv = *reinterpret_cast<const float4*>(&Hs[kc * 16 + kk][c]);
                acc[kk] += wv.x * hv.x + wv.y * hv.y + wv.z * hv.z + wv.w * hv.w;
            }
        }
        #pragma unroll
        for (int kk = 0; kk < 16; ++kk) {
            int k = kc * 16 + kk;
            if (k <= p) {
                float beta = tanhf(acc[kk] + bb);
                float av = alpha[((size_t)p * T_ + k) * B_ + b];
                float u = av * beta;
                hstore[((tri + (size_t)k) * B_ + b) * (size_t)E_ + tid] = u;  // U row (all reads staged above)
                cacc += u * emb[((size_t)k * B_ + b) * E_ + tid];
            }
        }
    }
    float pv = cacc * out_w[tid];
    #pragma unroll
    for (int off = 32; off > 0; off >>= 1) pv += __shfl_down(pv, off, 64);
    __shared__ float prr[4];
    if ((tid & 63) == 0) prr[tid >> 6] = pv;
    __syncthreads();
    if (tid == 0) outp[(size_t)b * P_ + p] = prr[0] + prr[1] + prr[2] + prr[3] + out_b[0];
}

// ---------------------------------------------------------------- K5c: weight[b,p,i] = (1/(p+1)) * sum_k (U[k]@M)[i] * x[b,k,i]
__global__ __launch_bounds__(256) void k_wout(const float* __restrict__ ustore,
                                              const float* __restrict__ Mmat,
                                              const float* __restrict__ x,
                                              float* __restrict__ out) {
    int p = 62 - (blockIdx.x >> 5);
    int b = blockIdx.x & 31;
    int tid = threadIdx.x;
    __shared__ float Ut[E_][68];   // [e][k] transposed, pad 68 for alignment + conflict spread
    size_t tri = (size_t)p * (p + 1) / 2;
    for (int k = 0; k <= p; ++k)
        Ut[tid][k] = ustore[((tri + (size_t)k) * B_ + b) * (size_t)E_ + tid];
    __syncthreads();
    float gacc = 0.f;
    int nch = (p >> 4) + 1;
    const float* xb = x + (size_t)b * T_ * 256;
    for (int kc = 0; kc < nch; ++kc) {
        float acc[16];
        #pragma unroll
        for (int kk = 0; kk < 16; ++kk) acc[kk] = 0.f;
        for (int e = 0; e < 256; ++e) {
            float m = Mmat[(size_t)e * 256 + tid];
            const float4* up = reinterpret_cast<const float4*>(&Ut[e][kc * 16]);
            float4 u0 = up[0], u1 = up[1], u2 = up[2], u3 = up[3];
            acc[0]  += u0.x * m; acc[1]  += u0.y * m; acc[2]  += u0.z * m; acc[3]  += u0.w * m;
            acc[4]  += u1.x * m; acc[5]  += u1.y * m; acc[6]  += u1.z * m; acc[7]  += u1.w * m;
            acc[8]  += u2.x * m; acc[9]  += u2.y * m; acc[10] += u2.z * m; acc[11] += u2.w * m;
            acc[12] += u3.x * m; acc[13] += u3.y * m; acc[14] += u3.z * m; acc[15] += u3.w * m;
        }
        #pragma unroll
        for (int kk = 0; kk < 16; ++kk) {
            int k = kc * 16 + kk;
            if (k <= p) gacc += acc[kk] * xb[(size_t)k * 256 + tid];
        }
    }
    out[2016 + ((size_t)b * P_ + p) * 256 + tid] = gacc / (float)(p + 1);
}

// ---------------------------------------------------------------- host
extern "C" void kernel_launch(void* const* d_in, const int* in_sizes, int n_in,
                              void* d_out, int out_size, void* d_ws, size_t ws_size,
                              hipStream_t stream) {
    const float* x       = (const float*)d_in[0];
    const float* emb_w   = (const float*)d_in[1];
    const float* emb_b   = (const float*)d_in[2];
    const float* a_wih   = (const float*)d_in[3];
    const float* a_whh   = (const float*)d_in[4];
    const float* a_bih   = (const float*)d_in[5];
    const float* a_bhh   = (const float*)d_in[6];
    const float* b_wih   = (const float*)d_in[7];
    const float* b_whh   = (const float*)d_in[8];
    const float* b_bih   = (const float*)d_in[9];
    const float* b_bhh   = (const float*)d_in[10];
    const float* alpha_w = (const float*)d_in[11];
    const float* alpha_b = (const float*)d_in[12];
    const float* beta_w  = (const float*)d_in[13];
    const float* beta_b  = (const float*)d_in[14];
    const float* out_w   = (const float*)d_in[15];
    const float* out_b   = (const float*)d_in[16];
    float* out = (float*)d_out;

    float* ws = (float*)d_ws;
    // ws layout (floats)
    float* emb    = ws;                       // 64*32*256      = 524288
    float* gia    = emb   + 524288;           // 2048*768       = 1572864
    float* gib    = gia   + 1572864;          // 1572864
    float* Mmat   = gib   + 1572864;          // 65536
    float* pre    = Mmat  + 65536;            // 63*64*32       = 129024
    float* alpha  = pre   + 129024;           // 129024
    float* hstore = alpha + 129024;           // 2016*32*256    = 16515072  (states, then U in-place)
    // total = 20508672 floats = ~82 MB

    k_prep<<<256, 256, 0, stream>>>(emb_w, out_w, Mmat);
    k_emb<<<2048, 256, 0, stream>>>(x, emb_w, emb_b, emb);
    k_gates<<<256, 256, 0, stream>>>(emb, a_wih, a_bih, b_wih, b_bih, gia, gib);
    k_gru<<<504, 256, 0, stream>>>(gia, gib, a_whh, a_bhh, b_whh, b_bhh,
                                   alpha_w, alpha_b, pre, hstore);
    k_softmax<<<2016, 64, 0, stream>>>(pre, alpha);
    k_beta<<<2016, 256, 0, stream>>>(hstore, beta_w, beta_b, alpha, emb, out_w, out_b, out);
    k_wout<<<2016, 256, 0, stream>>>(hstore, Mmat, x, out);
}

// Round 2
// 1463.642 us; speedup vs baseline: 3.3173x; 3.3173x over previous
//
#include <hip/hip_runtime.h>
#include <math.h>

// Problem constants: B=32, T=64, I=E=Ha=Hb=256, O=1, P=T-1=63
#define B_   32
#define T_   64
#define P_   63
#define E_   256
#define G3_  768

typedef _Float16 half8 __attribute__((ext_vector_type(8)));
typedef _Float16 half4 __attribute__((ext_vector_type(4)));
typedef float    f32x4 __attribute__((ext_vector_type(4)));

// LDS h-buffer index: [buf][hi/lo][row r][element c] (c pre-XOR-swizzled by caller)
#define HIDX(buf,hl,r,c) ((((buf)*2+(hl))*32+(r))*256+(c))

__device__ __forceinline__ float sigmoidf_(float x) { return 1.0f / (1.0f + __expf(-x)); }
__device__ __forceinline__ float tanhfast_(float x) { float e = __expf(2.0f*x); return 1.0f - 2.0f/(e + 1.0f); }

// ---------------------------------------------------------------- K0: M[e,i] = out_w0[e]*emb_w[e,i]
__global__ __launch_bounds__(256) void k_prep(const float* __restrict__ emb_w,
                                              const float* __restrict__ out_w,
                                              float* __restrict__ Mmat) {
    int e = blockIdx.x, i = threadIdx.x;
    Mmat[(size_t)e * 256 + i] = out_w[e] * emb_w[(size_t)e * 256 + i];
}

// ---------------------------------------------------------------- K1: emb[t,b,e] = emb_w @ x[b,t,:] + emb_b
__global__ __launch_bounds__(256) void k_emb(const float* __restrict__ x,
                                             const float* __restrict__ emb_w,
                                             const float* __restrict__ emb_b,
                                             float* __restrict__ emb) {
    int t = blockIdx.x >> 5, b = blockIdx.x & 31;
    int tid = threadIdx.x;
    __shared__ float xr[E_];
    xr[tid] = x[((size_t)b * T_ + t) * E_ + tid];
    __syncthreads();
    const float* wr = emb_w + (size_t)tid * E_;
    float acc = emb_b[tid];
    for (int c = 0; c < 256; c += 4) {
        float4 wv = *reinterpret_cast<const float4*>(wr + c);
        float4 xv = *reinterpret_cast<const float4*>(&xr[c]);
        acc += wv.x * xv.x + wv.y * xv.y + wv.z * xv.z + wv.w * xv.w;
    }
    emb[((size_t)t * B_ + b) * E_ + tid] = acc;
}

// ---------------------------------------------------------------- K2: input gates, written TRANSPOSED:
// giT[o][r] (o in [0,768), r = t*32+b in [0,2048)), with b_ih always folded and
// b_hh folded for r,z gates only (n-gate's b_hh enters inside the r* multiply).
__global__ __launch_bounds__(256) void k_gates(const float* __restrict__ emb,
                                               const float* __restrict__ awih, const float* __restrict__ abih,
                                               const float* __restrict__ abhh,
                                               const float* __restrict__ bwih, const float* __restrict__ bbih,
                                               const float* __restrict__ bbhh,
                                               float* __restrict__ giTa, float* __restrict__ giTb) {
    int r0 = blockIdx.x * 8;
    int tid = threadIdx.x;
    __shared__ float es[8][E_];
    for (int rr = 0; rr < 8; ++rr) es[rr][tid] = emb[(size_t)(r0 + rr) * E_ + tid];
    __syncthreads();
    for (int gs = 0; gs < 6; ++gs) {
        const float* W    = (gs < 3) ? awih : bwih;
        const float* bih  = (gs < 3) ? abih : bbih;
        const float* bhh  = (gs < 3) ? abhh : bbhh;
        float* giT        = (gs < 3) ? giTa : giTb;
        int gate = gs % 3;
        int grow = gate * 256 + tid;
        const float* wr = W + (size_t)grow * E_;
        float acc[8];
        #pragma unroll
        for (int rr = 0; rr < 8; ++rr) acc[rr] = 0.f;
        for (int c = 0; c < 256; c += 4) {
            float4 wv = *reinterpret_cast<const float4*>(wr + c);
            #pragma unroll
            for (int rr = 0; rr < 8; ++rr) {
                float4 ev = *reinterpret_cast<const float4*>(&es[rr][c]);
                acc[rr] += wv.x * ev.x + wv.y * ev.y + wv.z * ev.z + wv.w * ev.w;
            }
        }
        float bv = bih[grow] + ((gate < 2) ? bhh[grow] : 0.f);
        float* dst = giT + (size_t)grow * 2048 + r0;
        #pragma unroll
        for (int rr = 0; rr < 8; ++rr) dst[rr] = acc[rr] + bv;
    }
}

// ---------------------------------------------------------------- K2b: W_hh -> fp16, pre-swizzled to MFMA
// A-fragment order: wf[((otile*8+kc)*64 + lane)*8 + j] = (fp16) whh[otile*16 + (lane&15)][kc*32 + (lane>>4)*8 + j]
// so each A-frag load is one fully-coalesced 1KB wave read.
__global__ __launch_bounds__(64) void k_wfrag(const float* __restrict__ whh, _Float16* __restrict__ wf) {
    int ot = blockIdx.x >> 3, kc = blockIdx.x & 7, l = threadIdx.x;
    int orow = ot * 16 + (l & 15);
    int c0   = kc * 32 + (l >> 4) * 8;
    half8 v;
    #pragma unroll
    for (int j = 0; j < 8; ++j) v[j] = (_Float16)whh[(size_t)orow * 256 + c0 + j];
    *reinterpret_cast<half8*>(&wf[((size_t)(ot * 8 + kc) * 64 + l) * 8]) = v;
}

// ---------------------------------------------------------------- K3: triangular GRU chains, MFMA fp16-x2.
// block = (gru g, prefix p): 126 blocks x 512 threads (8 waves). All 32 batch rows per block.
// h state fp32 in registers (16/lane, D-fragment layout); per step h is split hi/lo fp16 into
// double-buffered XOR-swizzled LDS and the 768x256 gate matmul runs as mfma_f32_16x16x32_f16:
//   gates += Whi @ h_hi + Whi @ h_lo   (fp16-x2: W err ~2^-11, h err ~2^-21)
// GRU a: computes pre[p][t_in][b] inline (shuffle+LDS reduce). GRU b: streams h to hstore.
__global__ __launch_bounds__(512) void k_gru_f(
    const float* __restrict__ giTa, const float* __restrict__ giTb,
    const _Float16* __restrict__ wfa, const _Float16* __restrict__ wfb,
    const float* __restrict__ abhh, const float* __restrict__ bbhh,
    const float* __restrict__ alpha_w, const float* __restrict__ alpha_b,
    float* __restrict__ pre, float* __restrict__ hstore)
{
    int g   = blockIdx.x / 63;
    int p   = 62 - (int)(blockIdx.x % 63);
    int tid = threadIdx.x;
    int w = tid >> 6, l = tid & 63, lg = l >> 4, lr = l & 15;
    int dimw = w * 32;                       // this wave's 32 output dims (per gate)
    const float*    giT = g ? giTb : giTa;
    const _Float16* wf  = g ? wfb  : wfa;
    const float*    bhh = g ? bbhh : abhh;

    __shared__ _Float16 hsp[2 * 2 * 32 * 256];   // 64 KB: [buf][hi/lo][32 rows][256]
    __shared__ float red[2][32][9];

    float bhn[2][4], awv[2][4];
    #pragma unroll
    for (int dt = 0; dt < 2; ++dt)
        #pragma unroll
        for (int j = 0; j < 4; ++j) {
            int d = dimw + dt * 16 + lg * 4 + j;
            bhn[dt][j] = bhh[512 + d];
            awv[dt][j] = alpha_w[d];
        }
    float ab = alpha_b[0];

    float hreg[2][2][4];
    #pragma unroll
    for (int dt = 0; dt < 2; ++dt)
        #pragma unroll
        for (int rt = 0; rt < 2; ++rt)
            #pragma unroll
            for (int j = 0; j < 4; ++j) hreg[dt][rt][j] = 0.f;

    size_t tri = (size_t)p * (p + 1) / 2;

    for (int k = 0; k <= p; ++k) {
        int t_in = p - k;
        int wr = k & 1;          // write buffer this step; read buffer = wr^1
        // ---- top-of-step: drain step k-1's results (overlaps with this step's loads/MFMA)
        if (k > 0) {
            if (g == 0) {
                if (tid < 32) {
                    float s = 0.f;
                    #pragma unroll
                    for (int q = 0; q < 8; ++q) s += red[wr ^ 1][tid][q];
                    pre[((size_t)p * T_ + (t_in + 1)) * B_ + tid] = 0.5f * s + ab;
                }
            } else {
                int rr = tid >> 4, c0 = (tid & 15) << 4;
                int sw = (rr & 7) << 3;
                half8 h0 = *reinterpret_cast<const half8*>(&hsp[HIDX(wr ^ 1, 0, rr, (c0    ) ^ sw)]);
                half8 h1 = *reinterpret_cast<const half8*>(&hsp[HIDX(wr ^ 1, 0, rr, (c0 + 8) ^ sw)]);
                half8 l0 = *reinterpret_cast<const half8*>(&hsp[HIDX(wr ^ 1, 1, rr, (c0    ) ^ sw)]);
                half8 l1 = *reinterpret_cast<const half8*>(&hsp[HIDX(wr ^ 1, 1, rr, (c0 + 8) ^ sw)]);
                f32x4 v0, v1, v2, v3;
                #pragma unroll
                for (int j = 0; j < 4; ++j) {
                    v0[j] = (float)h0[j]     + (float)l0[j];
                    v1[j] = (float)h0[j + 4] + (float)l0[j + 4];
                    v2[j] = (float)h1[j]     + (float)l1[j];
                    v3[j] = (float)h1[j + 4] + (float)l1[j + 4];
                }
                float* dst = hstore + ((tri + (size_t)(k - 1)) * B_ + rr) * (size_t)E_ + c0;
                *reinterpret_cast<f32x4*>(dst)      = v0;
                *reinterpret_cast<f32x4*>(dst + 4)  = v1;
                *reinterpret_cast<f32x4*>(dst + 8)  = v2;
                *reinterpret_cast<f32x4*>(dst + 12) = v3;
            }
        }
        // ---- accumulator init: r,z from giT (C-in), n-hidden from bhn; gi_n staged to regs
        f32x4 acc[3][2][2];
        #pragma unroll
        for (int g3 = 0; g3 < 2; ++g3)
            #pragma unroll
            for (int dt = 0; dt < 2; ++dt)
                #pragma unroll
                for (int rt = 0; rt < 2; ++rt)
                    #pragma unroll
                    for (int j = 0; j < 4; ++j)
                        acc[g3][dt][rt][j] = giT[(size_t)(g3 * 256 + dimw + dt * 16 + lg * 4 + j) * 2048
                                                 + t_in * 32 + rt * 16 + lr];
        #pragma unroll
        for (int dt = 0; dt < 2; ++dt)
            #pragma unroll
            for (int rt = 0; rt < 2; ++rt)
                #pragma unroll
                for (int j = 0; j < 4; ++j) acc[2][dt][rt][j] = bhn[dt][j];
        float gin[2][2][4];
        #pragma unroll
        for (int dt = 0; dt < 2; ++dt)
            #pragma unroll
            for (int rt = 0; rt < 2; ++rt)
                #pragma unroll
                for (int j = 0; j < 4; ++j)
                    gin[dt][rt][j] = giT[(size_t)(512 + dimw + dt * 16 + lg * 4 + j) * 2048
                                         + t_in * 32 + rt * 16 + lr];
        // ---- MFMA: gates += Whi @ h_hi + Whi @ h_lo  (skip at k=0: h=0)
        if (k > 0) {
            int rb = wr ^ 1;
            #pragma unroll
            for (int kc = 0; kc < 8; ++kc) {
                half8 af[3][2];
                #pragma unroll
                for (int g3 = 0; g3 < 3; ++g3)
                    #pragma unroll
                    for (int dt = 0; dt < 2; ++dt) {
                        int ot = g3 * 16 + 2 * w + dt;
                        af[g3][dt] = *reinterpret_cast<const half8*>(&wf[((size_t)(ot * 8 + kc) * 64 + l) * 8]);
                    }
                half8 bh[2], bl[2];
                #pragma unroll
                for (int rt = 0; rt < 2; ++rt) {
                    int r = rt * 16 + lr;
                    int cb = (kc * 32 + lg * 8) ^ ((r & 7) << 3);
                    bh[rt] = *reinterpret_cast<const half8*>(&hsp[HIDX(rb, 0, r, cb)]);
                    bl[rt] = *reinterpret_cast<const half8*>(&hsp[HIDX(rb, 1, r, cb)]);
                }
                #pragma unroll
                for (int g3 = 0; g3 < 3; ++g3)
                    #pragma unroll
                    for (int dt = 0; dt < 2; ++dt)
                        #pragma unroll
                        for (int rt = 0; rt < 2; ++rt) {
                            acc[g3][dt][rt] = __builtin_amdgcn_mfma_f32_16x16x32_f16(af[g3][dt], bh[rt], acc[g3][dt][rt], 0, 0, 0);
                            acc[g3][dt][rt] = __builtin_amdgcn_mfma_f32_16x16x32_f16(af[g3][dt], bl[rt], acc[g3][dt][rt], 0, 0, 0);
                        }
            }
        }
        // ---- nonlinearity + state update + split-write to LDS
        #pragma unroll
        for (int dt = 0; dt < 2; ++dt)
            #pragma unroll
            for (int rt = 0; rt < 2; ++rt) {
                half4 hh, hl;
                #pragma unroll
                for (int j = 0; j < 4; ++j) {
                    float rg = sigmoidf_(acc[0][dt][rt][j]);
                    float zg = sigmoidf_(acc[1][dt][rt][j]);
                    float ng = tanhfast_(gin[dt][rt][j] + rg * acc[2][dt][rt][j]);
                    float h  = (k == 0) ? 0.f : hreg[dt][rt][j];
                    h = (1.f - zg) * ng + zg * h;
                    hreg[dt][rt][j] = h;
                    _Float16 hi = (_Float16)h;
                    hh[j] = hi;
                    hl[j] = (_Float16)(h - (float)hi);
                }
                int r  = rt * 16 + lr;
                int c0 = dimw + dt * 16 + lg * 4;
                int ce = c0 ^ ((r & 7) << 3);
                *reinterpret_cast<half4*>(&hsp[HIDX(wr, 0, r, ce)]) = hh;
                *reinterpret_cast<half4*>(&hsp[HIDX(wr, 1, r, ce)]) = hl;
            }
        if (g == 0) {
            #pragma unroll
            for (int rt = 0; rt < 2; ++rt) {
                float pa = 0.f;
                #pragma unroll
                for (int dt = 0; dt < 2; ++dt)
                    #pragma unroll
                    for (int j = 0; j < 4; ++j) pa += hreg[dt][rt][j] * awv[dt][j];
                pa += __shfl_xor(pa, 16, 64);
                pa += __shfl_xor(pa, 32, 64);
                if (l < 16) red[wr][rt * 16 + lr][w] = pa;
            }
        }
        __syncthreads();
    }
    // ---- epilogue: drain step p
    int wl = p & 1;
    if (g == 0) {
        if (tid < 32) {
            float s = 0.f;
            #pragma unroll
            for (int q = 0; q < 8; ++q) s += red[wl][tid][q];
            pre[((size_t)p * T_ + 0) * B_ + tid] = 0.5f * s + ab;
        }
    } else {
        int rr = tid >> 4, c0 = (tid & 15) << 4;
        int sw = (rr & 7) << 3;
        half8 h0 = *reinterpret_cast<const half8*>(&hsp[HIDX(wl, 0, rr, (c0    ) ^ sw)]);
        half8 h1 = *reinterpret_cast<const half8*>(&hsp[HIDX(wl, 0, rr, (c0 + 8) ^ sw)]);
        half8 l0 = *reinterpret_cast<const half8*>(&hsp[HIDX(wl, 1, rr, (c0    ) ^ sw)]);
        half8 l1 = *reinterpret_cast<const half8*>(&hsp[HIDX(wl, 1, rr, (c0 + 8) ^ sw)]);
        f32x4 v0, v1, v2, v3;
        #pragma unroll
        for (int j = 0; j < 4; ++j) {
            v0[j] = (float)h0[j]     + (float)l0[j];
            v1[j] = (float)h0[j + 4] + (float)l0[j + 4];
            v2[j] = (float)h1[j]     + (float)l1[j];
            v3[j] = (float)h1[j + 4] + (float)l1[j + 4];
        }
        float* dst = hstore + ((tri + (size_t)p) * B_ + rr) * (size_t)E_ + c0;
        *reinterpret_cast<f32x4*>(dst)      = v0;
        *reinterpret_cast<f32x4*>(dst + 4)  = v1;
        *reinterpret_cast<f32x4*>(dst + 8)  = v2;
        *reinterpret_cast<f32x4*>(dst + 12) = v3;
    }
}

// ---------------------------------------------------------------- K4: softmax over k<=p per (p,b)
__global__ __launch_bounds__(64) void k_softmax(const float* __restrict__ pre, float* __restrict__ alpha) {
    int p = blockIdx.x >> 5, b = blockIdx.x & 31;
    int k = threadIdx.x;
    float v = (k <= p) ? pre[((size_t)p * T_ + k) * B_ + b] : -3.4e38f;
    float m = v;
    #pragma unroll
    for (int off = 32; off > 0; off >>= 1) m = fmaxf(m, __shfl_xor(m, off, 64));
    float e = (k <= p) ? __expf(v - m) : 0.f;
    float s = e;
    #pragma unroll
    for (int off = 32; off > 0; off >>= 1) s += __shfl_xor(s, off, 64);
    if (k <= p) alpha[((size_t)p * T_ + k) * B_ + b] = e / s;
}

// ---------------------------------------------------------------- K5a: U = alpha * tanh(0.5*H @ beta_w^T + beta_b), in-place;
// also context c and pred. block=(p,b), thread=e, k in register chunks of 16.
__global__ __launch_bounds__(256) void k_beta(float* __restrict__ hstore,
                                              const float* __restrict__ beta_w, const float* __restrict__ beta_b,
                                              const float* __restrict__ alpha,
                                              const float* __restrict__ emb,
                                              const float* __restrict__ out_w, const float* __restrict__ out_b,
                                              float* __restrict__ outp) {
    int p = 62 - (blockIdx.x >> 5);
    int b = blockIdx.x & 31;
    int tid = threadIdx.x;
    __shared__ float Hs[64][E_];
    size_t tri = (size_t)p * (p + 1) / 2;
    for (int k = 0; k <= p; ++k)
        Hs[k][tid] = 0.5f * hstore[((tri + (size_t)(p - k)) * B_ + b) * (size_t)E_ + tid];
    __syncthreads();
    const float* wr = beta_w + (size_t)tid * E_;
    float bb = beta_b[tid];
    float cacc = 0.f;
    int nch = (p >> 4) + 1;
    for (int kc = 0; kc < nch; ++kc) {
        float acc[16];
        #pragma unroll
        for (int kk = 0; kk < 16; ++kk) acc[kk] = 0.f;
        for (int c = 0; c < 256; c += 4) {
            float4 wv = *reinterpret_cast<const float4*>(wr + c);
            #pragma unroll
            for (int kk = 0; kk < 16; ++kk) {
                float4 hv = *reinterpret_cast<const float4*>(&Hs[kc * 16 + kk][c]);
                acc[kk] += wv.x * hv.x + wv.y * hv.y + wv.z * hv.z + wv.w * hv.w;
            }
        }
        #pragma unroll
        for (int kk = 0; kk < 16; ++kk) {
            int k = kc * 16 + kk;
            if (k <= p) {
                float beta = tanhf(acc[kk] + bb);
                float av = alpha[((size_t)p * T_ + k) * B_ + b];
                float u = av * beta;
                hstore[((tri + (size_t)k) * B_ + b) * (size_t)E_ + tid] = u;
                cacc += u * emb[((size_t)k * B_ + b) * E_ + tid];
            }
        }
    }
    float pv = cacc * out_w[tid];
    #pragma unroll
    for (int off = 32; off > 0; off >>= 1) pv += __shfl_down(pv, off, 64);
    __shared__ float prr[4];
    if ((tid & 63) == 0) prr[tid >> 6] = pv;
    __syncthreads();
    if (tid == 0) outp[(size_t)b * P_ + p] = prr[0] + prr[1] + prr[2] + prr[3] + out_b[0];
}

// ---------------------------------------------------------------- K5c: weight[b,p,i] = (1/(p+1)) * sum_k (U[k]@M)[i] * x[b,k,i]
__global__ __launch_bounds__(256) void k_wout(const float* __restrict__ ustore,
                                              const float* __restrict__ Mmat,
                                              const float* __restrict__ x,
                                              float* __restrict__ out) {
    int p = 62 - (blockIdx.x >> 5);
    int b = blockIdx.x & 31;
    int tid = threadIdx.x;
    __shared__ float Ut[E_][68];
    size_t tri = (size_t)p * (p + 1) / 2;
    for (int k = 0; k <= p; ++k)
        Ut[tid][k] = ustore[((tri + (size_t)k) * B_ + b) * (size_t)E_ + tid];
    __syncthreads();
    float gacc = 0.f;
    int nch = (p >> 4) + 1;
    const float* xb = x + (size_t)b * T_ * 256;
    for (int kc = 0; kc < nch; ++kc) {
        float acc[16];
        #pragma unroll
        for (int kk = 0; kk < 16; ++kk) acc[kk] = 0.f;
        for (int e = 0; e < 256; ++e) {
            float m = Mmat[(size_t)e * 256 + tid];
            const float4* up = reinterpret_cast<const float4*>(&Ut[e][kc * 16]);
            float4 u0 = up[0], u1 = up[1], u2 = up[2], u3 = up[3];
            acc[0]  += u0.x * m; acc[1]  += u0.y * m; acc[2]  += u0.z * m; acc[3]  += u0.w * m;
            acc[4]  += u1.x * m; acc[5]  += u1.y * m; acc[6]  += u1.z * m; acc[7]  += u1.w * m;
            acc[8]  += u2.x * m; acc[9]  += u2.y * m; acc[10] += u2.z * m; acc[11] += u2.w * m;
            acc[12] += u3.x * m; acc[13] += u3.y * m; acc[14] += u3.z * m; acc[15] += u3.w * m;
        }
        #pragma unroll
        for (int kk = 0; kk < 16; ++kk) {
            int k = kc * 16 + kk;
            if (k <= p) gacc += acc[kk] * xb[(size_t)k * 256 + tid];
        }
    }
    out[2016 + ((size_t)b * P_ + p) * 256 + tid] = gacc / (float)(p + 1);
}

// ---------------------------------------------------------------- host
extern "C" void kernel_launch(void* const* d_in, const int* in_sizes, int n_in,
                              void* d_out, int out_size, void* d_ws, size_t ws_size,
                              hipStream_t stream) {
    const float* x       = (const float*)d_in[0];
    const float* emb_w   = (const float*)d_in[1];
    const float* emb_b   = (const float*)d_in[2];
    const float* a_wih   = (const float*)d_in[3];
    const float* a_whh   = (const float*)d_in[4];
    const float* a_bih   = (const float*)d_in[5];
    const float* a_bhh   = (const float*)d_in[6];
    const float* b_wih   = (const float*)d_in[7];
    const float* b_whh   = (const float*)d_in[8];
    const float* b_bih   = (const float*)d_in[9];
    const float* b_bhh   = (const float*)d_in[10];
    const float* alpha_w = (const float*)d_in[11];
    const float* alpha_b = (const float*)d_in[12];
    const float* beta_w  = (const float*)d_in[13];
    const float* beta_b  = (const float*)d_in[14];
    const float* out_w   = (const float*)d_in[15];
    const float* out_b   = (const float*)d_in[16];
    float* out = (float*)d_out;

    float* ws = (float*)d_ws;
    // ws layout (floats), total 20,705,280 floats = 82.8 MB
    float* emb    = ws;                       // 524288
    float* giTa   = emb    + 524288;          // 768*2048 = 1572864
    float* giTb   = giTa   + 1572864;         // 1572864
    float* Mmat   = giTb   + 1572864;         // 65536
    float* pre    = Mmat   + 65536;           // 129024
    float* alpha  = pre    + 129024;          // 129024
    _Float16* wfa = (_Float16*)(alpha + 129024);   // 196608 halves = 98304 floats
    _Float16* wfb = wfa + 196608;                  // 98304 floats
    float* hstore = (float*)(wfb + 196608);   // 2016*32*256 = 16515072

    k_prep<<<256, 256, 0, stream>>>(emb_w, out_w, Mmat);
    k_emb<<<2048, 256, 0, stream>>>(x, emb_w, emb_b, emb);
    k_gates<<<256, 256, 0, stream>>>(emb, a_wih, a_bih, a_bhh, b_wih, b_bih, b_bhh, giTa, giTb);
    k_wfrag<<<384, 64, 0, stream>>>(a_whh, wfa);
    k_wfrag<<<384, 64, 0, stream>>>(b_whh, wfb);
    k_gru_f<<<126, 512, 0, stream>>>(giTa, giTb, wfa, wfb, a_bhh, b_bhh,
                                     alpha_w, alpha_b, pre, hstore);
    k_softmax<<<2016, 64, 0, stream>>>(pre, alpha);
    k_beta<<<2016, 256, 0, stream>>>(hstore, beta_w, beta_b, alpha, emb, out_w, out_b, out);
    k_wout<<<2016, 256, 0, stream>>>(hstore, Mmat, x, out);
}

// Round 3
// 1399.673 us; speedup vs baseline: 3.4689x; 1.0457x over previous
//
#include <hip/hip_runtime.h>
#include <math.h>

// Problem constants: B=32, T=64, I=E=Ha=Hb=256, O=1, P=T-1=63
#define B_   32
#define T_   64
#define P_   63
#define E_   256
#define G3_  768

typedef _Float16 half8 __attribute__((ext_vector_type(8)));
typedef _Float16 half4 __attribute__((ext_vector_type(4)));
typedef float    f32x4 __attribute__((ext_vector_type(4)));

__device__ __forceinline__ float sigmoidf_(float x) { return 1.0f / (1.0f + __expf(-x)); }
__device__ __forceinline__ float tanhfast_(float x) { float e = __expf(2.0f*x); return 1.0f - 2.0f/(e + 1.0f); }

// ---------------------------------------------------------------- K0: M[e,i] = out_w0[e]*emb_w[e,i]
__global__ __launch_bounds__(256) void k_prep(const float* __restrict__ emb_w,
                                              const float* __restrict__ out_w,
                                              float* __restrict__ Mmat) {
    int e = blockIdx.x, i = threadIdx.x;
    Mmat[(size_t)e * 256 + i] = out_w[e] * emb_w[(size_t)e * 256 + i];
}

// ---------------------------------------------------------------- K1: emb[t,b,e] = emb_w @ x[b,t,:] + emb_b
__global__ __launch_bounds__(256) void k_emb(const float* __restrict__ x,
                                             const float* __restrict__ emb_w,
                                             const float* __restrict__ emb_b,
                                             float* __restrict__ emb) {
    int t = blockIdx.x >> 5, b = blockIdx.x & 31;
    int tid = threadIdx.x;
    __shared__ float xr[E_];
    xr[tid] = x[((size_t)b * T_ + t) * E_ + tid];
    __syncthreads();
    const float* wr = emb_w + (size_t)tid * E_;
    float acc = emb_b[tid];
    for (int c = 0; c < 256; c += 4) {
        float4 wv = *reinterpret_cast<const float4*>(wr + c);
        float4 xv = *reinterpret_cast<const float4*>(&xr[c]);
        acc += wv.x * xv.x + wv.y * xv.y + wv.z * xv.z + wv.w * xv.w;
    }
    emb[((size_t)t * B_ + b) * E_ + tid] = acc;
}

// ---------------------------------------------------------------- K2: input gates, written TRANSPOSED:
// giT[o][r] (o in [0,768), r = t*32+b), b_ih folded always; b_hh folded for r,z gates only.
__global__ __launch_bounds__(256) void k_gates(const float* __restrict__ emb,
                                               const float* __restrict__ awih, const float* __restrict__ abih,
                                               const float* __restrict__ abhh,
                                               const float* __restrict__ bwih, const float* __restrict__ bbih,
                                               const float* __restrict__ bbhh,
                                               float* __restrict__ giTa, float* __restrict__ giTb) {
    int r0 = blockIdx.x * 8;
    int tid = threadIdx.x;
    __shared__ float es[8][E_];
    for (int rr = 0; rr < 8; ++rr) es[rr][tid] = emb[(size_t)(r0 + rr) * E_ + tid];
    __syncthreads();
    for (int gs = 0; gs < 6; ++gs) {
        const float* W    = (gs < 3) ? awih : bwih;
        const float* bih  = (gs < 3) ? abih : bbih;
        const float* bhh  = (gs < 3) ? abhh : bbhh;
        float* giT        = (gs < 3) ? giTa : giTb;
        int gate = gs % 3;
        int grow = gate * 256 + tid;
        const float* wr = W + (size_t)grow * E_;
        float acc[8];
        #pragma unroll
        for (int rr = 0; rr < 8; ++rr) acc[rr] = 0.f;
        for (int c = 0; c < 256; c += 4) {
            float4 wv = *reinterpret_cast<const float4*>(wr + c);
            #pragma unroll
            for (int rr = 0; rr < 8; ++rr) {
                float4 ev = *reinterpret_cast<const float4*>(&es[rr][c]);
                acc[rr] += wv.x * ev.x + wv.y * ev.y + wv.z * ev.z + wv.w * ev.w;
            }
        }
        float bv = bih[grow] + ((gate < 2) ? bhh[grow] : 0.f);
        float* dst = giT + (size_t)grow * 2048 + r0;
        #pragma unroll
        for (int rr = 0; rr < 8; ++rr) dst[rr] = acc[rr] + bv;
    }
}

// ---------------------------------------------------------------- K2b: W_hh -> fp16 MFMA A-fragments
// wf[((ot*8+kc)*64 + lane)*8 + j] = (fp16) whh[ot*16 + (lane&15)][kc*32 + (lane>>4)*8 + j]
__global__ __launch_bounds__(64) void k_wfrag(const float* __restrict__ whh, _Float16* __restrict__ wf) {
    int ot = blockIdx.x >> 3, kc = blockIdx.x & 7, l = threadIdx.x;
    int orow = ot * 16 + (l & 15);
    int c0   = kc * 32 + (l >> 4) * 8;
    half8 v;
    #pragma unroll
    for (int j = 0; j < 8; ++j) v[j] = (_Float16)whh[(size_t)orow * 256 + c0 + j];
    *reinterpret_cast<half8*>(&wf[((size_t)(ot * 8 + kc) * 64 + l) * 8]) = v;
}

// ---------------------------------------------------------------- K3: triangular GRU chains, MFMA fp16 single-pass.
// block=(g,p): 126 blocks x 512 threads. h fp32 in regs (D-frag layout), fp16 copy in
// double-buffered swizzled LDS for next step's B-frags. acc starts 0; gi added at the
// nonlinearity so the 48 gi loads overlap the whole MFMA phase. W streamed from L2 with
// prefetch distance 2 kc; B-frags prefetched 1 kc ahead. One barrier per step.
__global__ __launch_bounds__(512, 2) void k_gru_f(
    const float* __restrict__ giTa, const float* __restrict__ giTb,
    const _Float16* __restrict__ wfa, const _Float16* __restrict__ wfb,
    const float* __restrict__ abhh, const float* __restrict__ bbhh,
    const float* __restrict__ alpha_w, const float* __restrict__ alpha_b,
    float* __restrict__ pre, float* __restrict__ hstore)
{
    int g   = blockIdx.x / 63;
    int p   = 62 - (int)(blockIdx.x % 63);
    int tid = threadIdx.x;
    int w = tid >> 6, l = tid & 63, lg = l >> 4, lr = l & 15;
    int dimw = w * 32;
    const float*    giT = g ? giTb : giTa;
    const _Float16* wf  = g ? wfb  : wfa;
    const float*    bhh = g ? bbhh : abhh;

    __shared__ _Float16 hsp[2 * 32 * 256];   // 32 KB: [buf][32 rows][256], XOR-swizzled cols
    __shared__ float red[2][32][9];

    float bhn[2][4], awv[2][4];
    #pragma unroll
    for (int dt = 0; dt < 2; ++dt)
        #pragma unroll
        for (int j = 0; j < 4; ++j) {
            int d = dimw + dt * 16 + lg * 4 + j;
            bhn[dt][j] = bhh[512 + d];
            awv[dt][j] = alpha_w[d];
        }
    float ab = alpha_b[0];

    float hreg[2][2][4];
    #pragma unroll
    for (int dt = 0; dt < 2; ++dt)
        #pragma unroll
        for (int rt = 0; rt < 2; ++rt)
            #pragma unroll
            for (int j = 0; j < 4; ++j) hreg[dt][rt][j] = 0.f;

    size_t tri = (size_t)p * (p + 1) / 2;

#define LOADAF(c) do { _Pragma("unroll") \
    for (int f = 0; f < 6; ++f) \
        af[c][f] = *reinterpret_cast<const half8*>( \
            &wf[(((size_t)((f >> 1) * 16 + 2 * w + (f & 1)) * 8 + (c)) * 64 + l) * 8]); } while (0)

#define READBH(c) do { _Pragma("unroll") \
    for (int rt = 0; rt < 2; ++rt) { \
        int r_ = rt * 16 + lr; \
        int cb_ = ((c) * 32 + lg * 8) ^ ((lr & 7) << 3); \
        bhv[c][rt] = *reinterpret_cast<const half8*>(&hsp[(rb * 32 + r_) * 256 + cb_]); } } while (0)

    for (int k = 0; k <= p; ++k) {
        int t_in = p - k;
        int wr = k & 1;           // LDS write buffer this step; read buffer rb = wr^1
        int rb = wr ^ 1;
        // ---- drain step k-1's pre (g=0): read red written before last barrier
        if (k > 0 && g == 0 && tid < 32) {
            float s = 0.f;
            #pragma unroll
            for (int q = 0; q < 8; ++q) s += red[rb][tid][q];
            pre[((size_t)p * T_ + (t_in + 1)) * B_ + tid] = 0.5f * s + ab;
        }
        // ---- issue gi loads (consumed at nonlinearity: covered by MFMA phase)
        float giv[3][2][2][4];
        {
            const float* gcol = giT + (size_t)t_in * 32;
            #pragma unroll
            for (int g3 = 0; g3 < 3; ++g3)
                #pragma unroll
                for (int dt = 0; dt < 2; ++dt)
                    #pragma unroll
                    for (int rt = 0; rt < 2; ++rt)
                        #pragma unroll
                        for (int j = 0; j < 4; ++j)
                            giv[g3][dt][rt][j] = gcol[(size_t)(g3 * 256 + dimw + dt * 16 + lg * 4 + j) * 2048
                                                      + rt * 16 + lr];
        }
        // ---- MFMA phase: acc = W @ h  (skip at k=0: h=0)
        f32x4 acc[3][2][2];
        #pragma unroll
        for (int g3 = 0; g3 < 3; ++g3)
            #pragma unroll
            for (int dt = 0; dt < 2; ++dt)
                #pragma unroll
                for (int rt = 0; rt < 2; ++rt)
                    #pragma unroll
                    for (int j = 0; j < 4; ++j) acc[g3][dt][rt][j] = 0.f;
        if (k > 0) {
            half8 af[8][6];
            half8 bhv[8][2];
            LOADAF(0); LOADAF(1);
            READBH(0);
            #pragma unroll
            for (int kc = 0; kc < 8; ++kc) {
                if (kc < 6) LOADAF(kc + 2);
                if (kc < 7) READBH(kc + 1);
                #pragma unroll
                for (int f = 0; f < 6; ++f)
                    #pragma unroll
                    for (int rt = 0; rt < 2; ++rt)
                        acc[f >> 1][f & 1][rt] =
                            __builtin_amdgcn_mfma_f32_16x16x32_f16(af[kc][f], bhv[kc][rt],
                                                                   acc[f >> 1][f & 1][rt], 0, 0, 0);
            }
        }
        // ---- nonlinearity + state update + fp16 LDS write + direct outputs
        #pragma unroll
        for (int dt = 0; dt < 2; ++dt)
            #pragma unroll
            for (int rt = 0; rt < 2; ++rt) {
                half4 hh;
                #pragma unroll
                for (int j = 0; j < 4; ++j) {
                    float rg = sigmoidf_(acc[0][dt][rt][j] + giv[0][dt][rt][j]);
                    float zg = sigmoidf_(acc[1][dt][rt][j] + giv[1][dt][rt][j]);
                    float ng = tanhfast_(giv[2][dt][rt][j] + rg * (acc[2][dt][rt][j] + bhn[dt][j]));
                    float h  = (1.f - zg) * ng + zg * hreg[dt][rt][j];
                    hreg[dt][rt][j] = h;
                    hh[j] = (_Float16)h;
                }
                int r  = rt * 16 + lr;
                int ce = (dimw + dt * 16 + lg * 4) ^ ((lr & 7) << 3);
                *reinterpret_cast<half4*>(&hsp[(wr * 32 + r) * 256 + ce]) = hh;
            }
        if (g) {
            // stream h (fp32) straight from registers to hstore
            #pragma unroll
            for (int rt = 0; rt < 2; ++rt) {
                float* dst = hstore + ((tri + (size_t)k) * B_ + (rt * 16 + lr)) * (size_t)E_ + dimw + lg * 4;
                #pragma unroll
                for (int dt = 0; dt < 2; ++dt) {
                    f32x4 v;
                    #pragma unroll
                    for (int j = 0; j < 4; ++j) v[j] = hreg[dt][rt][j];
                    *reinterpret_cast<f32x4*>(dst + dt * 16) = v;
                }
            }
        } else {
            #pragma unroll
            for (int rt = 0; rt < 2; ++rt) {
                float pa = 0.f;
                #pragma unroll
                for (int dt = 0; dt < 2; ++dt)
                    #pragma unroll
                    for (int j = 0; j < 4; ++j) pa += hreg[dt][rt][j] * awv[dt][j];
                pa += __shfl_xor(pa, 16, 64);
                pa += __shfl_xor(pa, 32, 64);
                if (l < 16) red[wr][rt * 16 + lr][w] = pa;
            }
        }
        __syncthreads();
    }
    // ---- epilogue: drain step p's pre
    if (g == 0 && tid < 32) {
        float s = 0.f;
        #pragma unroll
        for (int q = 0; q < 8; ++q) s += red[p & 1][tid][q];
        pre[((size_t)p * T_ + 0) * B_ + tid] = 0.5f * s + ab;
    }
#undef LOADAF
#undef READBH
}

// ---------------------------------------------------------------- K4: softmax over k<=p per (p,b)
__global__ __launch_bounds__(64) void k_softmax(const float* __restrict__ pre, float* __restrict__ alpha) {
    int p = blockIdx.x >> 5, b = blockIdx.x & 31;
    int k = threadIdx.x;
    float v = (k <= p) ? pre[((size_t)p * T_ + k) * B_ + b] : -3.4e38f;
    float m = v;
    #pragma unroll
    for (int off = 32; off > 0; off >>= 1) m = fmaxf(m, __shfl_xor(m, off, 64));
    float e = (k <= p) ? __expf(v - m) : 0.f;
    float s = e;
    #pragma unroll
    for (int off = 32; off > 0; off >>= 1) s += __shfl_xor(s, off, 64);
    if (k <= p) alpha[((size_t)p * T_ + k) * B_ + b] = e / s;
}

// ---------------------------------------------------------------- K5a: U = alpha * tanh(0.5*H @ beta_w^T + beta_b), in-place;
// also context c and pred. block=(p,b), thread=e, k in register chunks of 16.
__global__ __launch_bounds__(256) void k_beta(float* __restrict__ hstore,
                                              const float* __restrict__ beta_w, const float* __restrict__ beta_b,
                                              const float* __restrict__ alpha,
                                              const float* __restrict__ emb,
                                              const float* __restrict__ out_w, const float* __restrict__ out_b,
                                              float* __restrict__ outp) {
    int p = 62 - (blockIdx.x >> 5);
    int b = blockIdx.x & 31;
    int tid = threadIdx.x;
    __shared__ float Hs[64][E_];
    size_t tri = (size_t)p * (p + 1) / 2;
    for (int k = 0; k <= p; ++k)
        Hs[k][tid] = 0.5f * hstore[((tri + (size_t)(p - k)) * B_ + b) * (size_t)E_ + tid];
    __syncthreads();
    const float* wr = beta_w + (size_t)tid * E_;
    float bb = beta_b[tid];
    float cacc = 0.f;
    int nch = (p >> 4) + 1;
    for (int kc = 0; kc < nch; ++kc) {
        float acc[16];
        #pragma unroll
        for (int kk = 0; kk < 16; ++kk) acc[kk] = 0.f;
        for (int c = 0; c < 256; c += 4) {
            float4 wv = *reinterpret_cast<const float4*>(wr + c);
            #pragma unroll
            for (int kk = 0; kk < 16; ++kk) {
                float4 hv = *reinterpret_cast<const float4*>(&Hs[kc * 16 + kk][c]);
                acc[kk] += wv.x * hv.x + wv.y * hv.y + wv.z * hv.z + wv.w * hv.w;
            }
        }
        #pragma unroll
        for (int kk = 0; kk < 16; ++kk) {
            int k = kc * 16 + kk;
            if (k <= p) {
                float beta = tanhf(acc[kk] + bb);
                float av = alpha[((size_t)p * T_ + k) * B_ + b];
                float u = av * beta;
                hstore[((tri + (size_t)k) * B_ + b) * (size_t)E_ + tid] = u;
                cacc += u * emb[((size_t)k * B_ + b) * E_ + tid];
            }
        }
    }
    float pv = cacc * out_w[tid];
    #pragma unroll
    for (int off = 32; off > 0; off >>= 1) pv += __shfl_down(pv, off, 64);
    __shared__ float prr[4];
    if ((tid & 63) == 0) prr[tid >> 6] = pv;
    __syncthreads();
    if (tid == 0) outp[(size_t)b * P_ + p] = prr[0] + prr[1] + prr[2] + prr[3] + out_b[0];
}

// ---------------------------------------------------------------- K5c: weight[b,p,i] = (1/(p+1)) * sum_k (U[k]@M)[i] * x[b,k,i]
__global__ __launch_bounds__(256) void k_wout(const float* __restrict__ ustore,
                                              const float* __restrict__ Mmat,
                                              const float* __restrict__ x,
                                              float* __restrict__ out) {
    int p = 62 - (blockIdx.x >> 5);
    int b = blockIdx.x & 31;
    int tid = threadIdx.x;
    __shared__ float Ut[E_][68];
    size_t tri = (size_t)p * (p + 1) / 2;
    for (int k = 0; k <= p; ++k)
        Ut[tid][k] = ustore[((tri + (size_t)k) * B_ + b) * (size_t)E_ + tid];
    __syncthreads();
    float gacc = 0.f;
    int nch = (p >> 4) + 1;
    const float* xb = x + (size_t)b * T_ * 256;
    for (int kc = 0; kc < nch; ++kc) {
        float acc[16];
        #pragma unroll
        for (int kk = 0; kk < 16; ++kk) acc[kk] = 0.f;
        for (int e = 0; e < 256; ++e) {
            float m = Mmat[(size_t)e * 256 + tid];
            const float4* up = reinterpret_cast<const float4*>(&Ut[e][kc * 16]);
            float4 u0 = up[0], u1 = up[1], u2 = up[2], u3 = up[3];
            acc[0]  += u0.x * m; acc[1]  += u0.y * m; acc[2]  += u0.z * m; acc[3]  += u0.w * m;
            acc[4]  += u1.x * m; acc[5]  += u1.y * m; acc[6]  += u1.z * m; acc[7]  += u1.w * m;
            acc[8]  += u2.x * m; acc[9]  += u2.y * m; acc[10] += u2.z * m; acc[11] += u2.w * m;
            acc[12] += u3.x * m; acc[13] += u3.y * m; acc[14] += u3.z * m; acc[15] += u3.w * m;
        }
        #pragma unroll
        for (int kk = 0; kk < 16; ++kk) {
            int k = kc * 16 + kk;
            if (k <= p) gacc += acc[kk] * xb[(size_t)k * 256 + tid];
        }
    }
    out[2016 + ((size_t)b * P_ + p) * 256 + tid] = gacc / (float)(p + 1);
}

// ---------------------------------------------------------------- host
extern "C" void kernel_launch(void* const* d_in, const int* in_sizes, int n_in,
                              void* d_out, int out_size, void* d_ws, size_t ws_size,
                              hipStream_t stream) {
    const float* x       = (const float*)d_in[0];
    const float* emb_w   = (const float*)d_in[1];
    const float* emb_b   = (const float*)d_in[2];
    const float* a_wih   = (const float*)d_in[3];
    const float* a_whh   = (const float*)d_in[4];
    const float* a_bih   = (const float*)d_in[5];
    const float* a_bhh   = (const float*)d_in[6];
    const float* b_wih   = (const float*)d_in[7];
    const float* b_whh   = (const float*)d_in[8];
    const float* b_bih   = (const float*)d_in[9];
    const float* b_bhh   = (const float*)d_in[10];
    const float* alpha_w = (const float*)d_in[11];
    const float* alpha_b = (const float*)d_in[12];
    const float* beta_w  = (const float*)d_in[13];
    const float* beta_b  = (const float*)d_in[14];
    const float* out_w   = (const float*)d_in[15];
    const float* out_b   = (const float*)d_in[16];
    float* out = (float*)d_out;

    float* ws = (float*)d_ws;
    // ws layout (floats), total ~82.8 MB
    float* emb    = ws;                       // 524288
    float* giTa   = emb    + 524288;          // 768*2048 = 1572864
    float* giTb   = giTa   + 1572864;         // 1572864
    float* Mmat   = giTb   + 1572864;         // 65536
    float* pre    = Mmat   + 65536;           // 129024
    float* alpha  = pre    + 129024;          // 129024
    _Float16* wfa = (_Float16*)(alpha + 129024);   // 196608 halves
    _Float16* wfb = wfa + 196608;                  // 196608 halves
    float* hstore = (float*)(wfb + 196608);   // 2016*32*256 = 16515072

    k_prep<<<256, 256, 0, stream>>>(emb_w, out_w, Mmat);
    k_emb<<<2048, 256, 0, stream>>>(x, emb_w, emb_b, emb);
    k_gates<<<256, 256, 0, stream>>>(emb, a_wih, a_bih, a_bhh, b_wih, b_bih, b_bhh, giTa, giTb);
    k_wfrag<<<384, 64, 0, stream>>>(a_whh, wfa);
    k_wfrag<<<384, 64, 0, stream>>>(b_whh, wfb);
    k_gru_f<<<126, 512, 0, stream>>>(giTa, giTb, wfa, wfb, a_bhh, b_bhh,
                                     alpha_w, alpha_b, pre, hstore);
    k_softmax<<<2016, 64, 0, stream>>>(pre, alpha);
    k_beta<<<2016, 256, 0, stream>>>(hstore, beta_w, beta_b, alpha, emb, out_w, out_b, out);
    k_wout<<<2016, 256, 0, stream>>>(hstore, Mmat, x, out);
}

// Round 4
// 1092.059 us; speedup vs baseline: 4.4460x; 1.2817x over previous
//
#include <hip/hip_runtime.h>
#include <math.h>

// Problem constants: B=32, T=64, I=E=Ha=Hb=256, O=1, P=T-1=63
#define B_   32
#define T_   64
#define P_   63
#define E_   256
#define G3_  768

typedef _Float16 half8 __attribute__((ext_vector_type(8)));
typedef _Float16 half4 __attribute__((ext_vector_type(4)));
typedef float    f32x4 __attribute__((ext_vector_type(4)));

__device__ __forceinline__ float sigmoidf_(float x) { return 1.0f / (1.0f + __expf(-x)); }
__device__ __forceinline__ float tanhfast_(float x) { float e = __expf(2.0f*x); return 1.0f - 2.0f/(e + 1.0f); }

// Barrier WITHOUT vmcnt drain: only LDS ops must be visible across it.
// Global loads/stores keep flowing across steps (counted vmcnt inserted by compiler at use).
__device__ __forceinline__ void barrier_lds_() {
    asm volatile("" ::: "memory");
    asm volatile("s_waitcnt lgkmcnt(0)" ::: "memory");
    __builtin_amdgcn_s_barrier();
    asm volatile("" ::: "memory");
}

// ---------------------------------------------------------------- K0: M[e,i] = out_w0[e]*emb_w[e,i]
__global__ __launch_bounds__(256) void k_prep(const float* __restrict__ emb_w,
                                              const float* __restrict__ out_w,
                                              float* __restrict__ Mmat) {
    int e = blockIdx.x, i = threadIdx.x;
    Mmat[(size_t)e * 256 + i] = out_w[e] * emb_w[(size_t)e * 256 + i];
}

// ---------------------------------------------------------------- K1: emb[t,b,e] = emb_w @ x[b,t,:] + emb_b
__global__ __launch_bounds__(256) void k_emb(const float* __restrict__ x,
                                             const float* __restrict__ emb_w,
                                             const float* __restrict__ emb_b,
                                             float* __restrict__ emb) {
    int t = blockIdx.x >> 5, b = blockIdx.x & 31;
    int tid = threadIdx.x;
    __shared__ float xr[E_];
    xr[tid] = x[((size_t)b * T_ + t) * E_ + tid];
    __syncthreads();
    const float* wr = emb_w + (size_t)tid * E_;
    float acc = emb_b[tid];
    for (int c = 0; c < 256; c += 4) {
        float4 wv = *reinterpret_cast<const float4*>(wr + c);
        float4 xv = *reinterpret_cast<const float4*>(&xr[c]);
        acc += wv.x * xv.x + wv.y * xv.y + wv.z * xv.z + wv.w * xv.w;
    }
    emb[((size_t)t * B_ + b) * E_ + tid] = acc;
}

// ---------------------------------------------------------------- K2: input gates -> fp16, transposed [o][r]
// b_ih folded always; b_hh folded for r,z gates only (n-gate's b_hh enters inside r*).
__global__ __launch_bounds__(256) void k_gates(const float* __restrict__ emb,
                                               const float* __restrict__ awih, const float* __restrict__ abih,
                                               const float* __restrict__ abhh,
                                               const float* __restrict__ bwih, const float* __restrict__ bbih,
                                               const float* __restrict__ bbhh,
                                               _Float16* __restrict__ giTa, _Float16* __restrict__ giTb) {
    int r0 = blockIdx.x * 8;
    int tid = threadIdx.x;
    __shared__ float es[8][E_];
    for (int rr = 0; rr < 8; ++rr) es[rr][tid] = emb[(size_t)(r0 + rr) * E_ + tid];
    __syncthreads();
    for (int gs = 0; gs < 6; ++gs) {
        const float* W    = (gs < 3) ? awih : bwih;
        const float* bih  = (gs < 3) ? abih : bbih;
        const float* bhh  = (gs < 3) ? abhh : bbhh;
        _Float16* giT     = (gs < 3) ? giTa : giTb;
        int gate = gs % 3;
        int grow = gate * 256 + tid;
        const float* wr = W + (size_t)grow * E_;
        float acc[8];
        #pragma unroll
        for (int rr = 0; rr < 8; ++rr) acc[rr] = 0.f;
        for (int c = 0; c < 256; c += 4) {
            float4 wv = *reinterpret_cast<const float4*>(wr + c);
            #pragma unroll
            for (int rr = 0; rr < 8; ++rr) {
                float4 ev = *reinterpret_cast<const float4*>(&es[rr][c]);
                acc[rr] += wv.x * ev.x + wv.y * ev.y + wv.z * ev.z + wv.w * ev.w;
            }
        }
        float bv = bih[grow] + ((gate < 2) ? bhh[grow] : 0.f);
        _Float16* dst = giT + (size_t)grow * 2048 + r0;
        #pragma unroll
        for (int rr = 0; rr < 8; ++rr) dst[rr] = (_Float16)(acc[rr] + bv);
    }
}

// ---------------------------------------------------------------- K2b: W_hh -> fp16 MFMA A-fragments
// wf[((ot*8+kc)*64 + lane)*8 + j] = (fp16) whh[ot*16 + (lane&15)][kc*32 + (lane>>4)*8 + j]
__global__ __launch_bounds__(64) void k_wfrag(const float* __restrict__ whh, _Float16* __restrict__ wf) {
    int ot = blockIdx.x >> 3, kc = blockIdx.x & 7, l = threadIdx.x;
    int orow = ot * 16 + (l & 15);
    int c0   = kc * 32 + (l >> 4) * 8;
    half8 v;
    #pragma unroll
    for (int j = 0; j < 8; ++j) v[j] = (_Float16)whh[(size_t)orow * 256 + c0 + j];
    *reinterpret_cast<half8*>(&wf[((size_t)(ot * 8 + kc) * 64 + l) * 8]) = v;
}

// ---------------------------------------------------------------- K2c: pack gi into per-(t,wave,chunk,lane) order.
// chunk c=g3*2+dt (6 chunks of 8: e=rt*4+j). gp[((t*8+w)*6 + c)*512 + l*8 + e]
// -> each k_gru_f thread does 6 fully-coalesced 16B loads per step.
__global__ __launch_bounds__(512) void k_gipack(const _Float16* __restrict__ gA, const _Float16* __restrict__ gB,
                                                _Float16* __restrict__ pA, _Float16* __restrict__ pB) {
    int g = blockIdx.x >> 6, t = blockIdx.x & 63;
    const _Float16* src = g ? gB : gA;
    _Float16*       dst = g ? pB : pA;
    int tid = threadIdx.x, w = tid >> 6, l = tid & 63, lg = l >> 4, lr = l & 15;
    #pragma unroll
    for (int c = 0; c < 6; ++c) {
        int g3 = c >> 1, dt = c & 1;
        half8 v;
        #pragma unroll
        for (int e = 0; e < 8; ++e) {
            int rt = e >> 2, j = e & 3;
            v[e] = src[(size_t)(g3 * 256 + w * 32 + dt * 16 + lg * 4 + j) * 2048 + t * 32 + rt * 16 + lr];
        }
        *reinterpret_cast<half8*>(&dst[((size_t)(t * 8 + w) * 6 + c) * 512 + l * 8]) = v;
    }
}

// ---------------------------------------------------------------- K3: triangular GRU chains, MFMA fp16.
// block=(g,p): 126 blocks x 512 threads. h fp32 in regs (D-frag layout), fp16 copy in
// double-buffered swizzled LDS for next step's B-frags. One lgkm-only barrier per step:
// global loads (gi, W) and stores (hstore, pre) pipeline ACROSS steps.
__global__ __launch_bounds__(512, 2) void k_gru_f(
    const _Float16* __restrict__ gpa, const _Float16* __restrict__ gpb,
    const _Float16* __restrict__ wfa, const _Float16* __restrict__ wfb,
    const float* __restrict__ abhh, const float* __restrict__ bbhh,
    const float* __restrict__ alpha_w, const float* __restrict__ alpha_b,
    float* __restrict__ pre, float* __restrict__ hstore)
{
    int g   = blockIdx.x / 63;
    int p   = 62 - (int)(blockIdx.x % 63);
    int tid = threadIdx.x;
    int w = tid >> 6, l = tid & 63, lg = l >> 4, lr = l & 15;
    int dimw = w * 32;
    const _Float16* gp  = g ? gpb : gpa;
    const _Float16* wf  = g ? wfb : wfa;
    const float*    bhh = g ? bbhh : abhh;

    __shared__ _Float16 hsp[2 * 32 * 256];   // 32 KB: [buf][32 rows][256], XOR-swizzled cols
    __shared__ float red[2][32][9];

    float bhn[2][4], awv[2][4];
    #pragma unroll
    for (int dt = 0; dt < 2; ++dt)
        #pragma unroll
        for (int j = 0; j < 4; ++j) {
            int d = dimw + dt * 16 + lg * 4 + j;
            bhn[dt][j] = bhh[512 + d];
            awv[dt][j] = alpha_w[d];
        }
    float ab = alpha_b[0];

    float hreg[2][2][4];
    #pragma unroll
    for (int dt = 0; dt < 2; ++dt)
        #pragma unroll
        for (int rt = 0; rt < 2; ++rt)
            #pragma unroll
            for (int j = 0; j < 4; ++j) hreg[dt][rt][j] = 0.f;

    size_t tri = (size_t)p * (p + 1) / 2;

#define LOADAF(c) do { _Pragma("unroll") \
    for (int f = 0; f < 6; ++f) \
        af[c][f] = *reinterpret_cast<const half8*>( \
            &wf[(((size_t)((f >> 1) * 16 + 2 * w + (f & 1)) * 8 + (c)) * 64 + l) * 8]); } while (0)

#define READBH(c) do { _Pragma("unroll") \
    for (int rt = 0; rt < 2; ++rt) { \
        int r_ = rt * 16 + lr; \
        int cb_ = ((c) * 32 + lg * 8) ^ ((lr & 7) << 3); \
        bhv[c][rt] = *reinterpret_cast<const half8*>(&hsp[(rb * 32 + r_) * 256 + cb_]); } } while (0)

    for (int k = 0; k <= p; ++k) {
        int t_in = p - k;
        int wr = k & 1;           // LDS write buffer this step; read buffer rb = wr^1
        int rb = wr ^ 1;
        // ---- drain step k-1's pre (g=0): red written before last barrier
        if (k > 0 && g == 0 && tid < 32) {
            float s = 0.f;
            #pragma unroll
            for (int q = 0; q < 8; ++q) s += red[rb][tid][q];
            pre[((size_t)p * T_ + (t_in + 1)) * B_ + tid] = 0.5f * s + ab;
        }
        // ---- issue gi loads (fp16, packed; consumed at nonlinearity, covered by MFMA phase)
        half8 gch[6];
        {
            const _Float16* gq = gp + ((size_t)(t_in * 8 + w) * 6) * 512 + l * 8;
            #pragma unroll
            for (int c = 0; c < 6; ++c)
                gch[c] = *reinterpret_cast<const half8*>(gq + (size_t)c * 512);
        }
        // ---- MFMA phase: acc = W @ h  (skip at k=0: h=0)
        f32x4 acc[3][2][2];
        #pragma unroll
        for (int g3 = 0; g3 < 3; ++g3)
            #pragma unroll
            for (int dt = 0; dt < 2; ++dt)
                #pragma unroll
                for (int rt = 0; rt < 2; ++rt)
                    #pragma unroll
                    for (int j = 0; j < 4; ++j) acc[g3][dt][rt][j] = 0.f;
        if (k > 0) {
            half8 af[8][6];
            half8 bhv[8][2];
            LOADAF(0); LOADAF(1);
            READBH(0);
            #pragma unroll
            for (int kc = 0; kc < 8; ++kc) {
                if (kc < 6) LOADAF(kc + 2);
                if (kc < 7) READBH(kc + 1);
                #pragma unroll
                for (int f = 0; f < 6; ++f)
                    #pragma unroll
                    for (int rt = 0; rt < 2; ++rt)
                        acc[f >> 1][f & 1][rt] =
                            __builtin_amdgcn_mfma_f32_16x16x32_f16(af[kc][f], bhv[kc][rt],
                                                                   acc[f >> 1][f & 1][rt], 0, 0, 0);
            }
        }
        // ---- nonlinearity + state update + fp16 LDS write + direct global outputs
        #pragma unroll
        for (int dt = 0; dt < 2; ++dt)
            #pragma unroll
            for (int rt = 0; rt < 2; ++rt) {
                half4 hh;
                #pragma unroll
                for (int j = 0; j < 4; ++j) {
                    float rg = sigmoidf_(acc[0][dt][rt][j] + (float)gch[dt][rt * 4 + j]);
                    float zg = sigmoidf_(acc[1][dt][rt][j] + (float)gch[2 + dt][rt * 4 + j]);
                    float ng = tanhfast_((float)gch[4 + dt][rt * 4 + j] + rg * (acc[2][dt][rt][j] + bhn[dt][j]));
                    float h  = (1.f - zg) * ng + zg * hreg[dt][rt][j];
                    hreg[dt][rt][j] = h;
                    hh[j] = (_Float16)h;
                }
                int r  = rt * 16 + lr;
                int ce = (dimw + dt * 16 + lg * 4) ^ ((lr & 7) << 3);
                *reinterpret_cast<half4*>(&hsp[(wr * 32 + r) * 256 + ce]) = hh;
            }
        if (g) {
            // stream h (fp32) straight from registers to hstore (no wait: fire and forget)
            #pragma unroll
            for (int rt = 0; rt < 2; ++rt) {
                float* dst = hstore + ((tri + (size_t)k) * B_ + (rt * 16 + lr)) * (size_t)E_ + dimw + lg * 4;
                #pragma unroll
                for (int dt = 0; dt < 2; ++dt) {
                    f32x4 v;
                    #pragma unroll
                    for (int j = 0; j < 4; ++j) v[j] = hreg[dt][rt][j];
                    *reinterpret_cast<f32x4*>(dst + dt * 16) = v;
                }
            }
        } else {
            #pragma unroll
            for (int rt = 0; rt < 2; ++rt) {
                float pa = 0.f;
                #pragma unroll
                for (int dt = 0; dt < 2; ++dt)
                    #pragma unroll
                    for (int j = 0; j < 4; ++j) pa += hreg[dt][rt][j] * awv[dt][j];
                pa += __shfl_xor(pa, 16, 64);
                pa += __shfl_xor(pa, 32, 64);
                if (l < 16) red[wr][rt * 16 + lr][w] = pa;
            }
        }
        barrier_lds_();
    }
    // ---- epilogue: drain step p's pre
    if (g == 0 && tid < 32) {
        float s = 0.f;
        #pragma unroll
        for (int q = 0; q < 8; ++q) s += red[p & 1][tid][q];
        pre[((size_t)p * T_ + 0) * B_ + tid] = 0.5f * s + ab;
    }
#undef LOADAF
#undef READBH
}

// ---------------------------------------------------------------- K4: softmax over k<=p per (p,b)
__global__ __launch_bounds__(64) void k_softmax(const float* __restrict__ pre, float* __restrict__ alpha) {
    int p = blockIdx.x >> 5, b = blockIdx.x & 31;
    int k = threadIdx.x;
    float v = (k <= p) ? pre[((size_t)p * T_ + k) * B_ + b] : -3.4e38f;
    float m = v;
    #pragma unroll
    for (int off = 32; off > 0; off >>= 1) m = fmaxf(m, __shfl_xor(m, off, 64));
    float e = (k <= p) ? __expf(v - m) : 0.f;
    float s = e;
    #pragma unroll
    for (int off = 32; off > 0; off >>= 1) s += __shfl_xor(s, off, 64);
    if (k <= p) alpha[((size_t)p * T_ + k) * B_ + b] = e / s;
}

// ---------------------------------------------------------------- K5a: U = alpha * tanh(0.5*H @ beta_w^T + beta_b), in-place;
// also context c and pred. block=(p,b), thread=e, k in register chunks of 16.
__global__ __launch_bounds__(256) void k_beta(float* __restrict__ hstore,
                                              const float* __restrict__ beta_w, const float* __restrict__ beta_b,
                                              const float* __restrict__ alpha,
                                              const float* __restrict__ emb,
                                              const float* __restrict__ out_w, const float* __restrict__ out_b,
                                              float* __restrict__ outp) {
    int p = 62 - (blockIdx.x >> 5);
    int b = blockIdx.x & 31;
    int tid = threadIdx.x;
    __shared__ float Hs[64][E_];
    size_t tri = (size_t)p * (p + 1) / 2;
    for (int k = 0; k <= p; ++k)
        Hs[k][tid] = 0.5f * hstore[((tri + (size_t)(p - k)) * B_ + b) * (size_t)E_ + tid];
    __syncthreads();
    const float* wr = beta_w + (size_t)tid * E_;
    float bb = beta_b[tid];
    float cacc = 0.f;
    int nch = (p >> 4) + 1;
    for (int kc = 0; kc < nch; ++kc) {
        float acc[16];
        #pragma unroll
        for (int kk = 0; kk < 16; ++kk) acc[kk] = 0.f;
        for (int c = 0; c < 256; c += 4) {
            float4 wv = *reinterpret_cast<const float4*>(wr + c);
            #pragma unroll
            for (int kk = 0; kk < 16; ++kk) {
                float4 hv = *reinterpret_cast<const float4*>(&Hs[kc * 16 + kk][c]);
                acc[kk] += wv.x * hv.x + wv.y * hv.y + wv.z * hv.z + wv.w * hv.w;
            }
        }
        #pragma unroll
        for (int kk = 0; kk < 16; ++kk) {
            int k = kc * 16 + kk;
            if (k <= p) {
                float beta = tanhf(acc[kk] + bb);
                float av = alpha[((size_t)p * T_ + k) * B_ + b];
                float u = av * beta;
                hstore[((tri + (size_t)k) * B_ + b) * (size_t)E_ + tid] = u;
                cacc += u * emb[((size_t)k * B_ + b) * E_ + tid];
            }
        }
    }
    float pv = cacc * out_w[tid];
    #pragma unroll
    for (int off = 32; off > 0; off >>= 1) pv += __shfl_down(pv, off, 64);
    __shared__ float prr[4];
    if ((tid & 63) == 0) prr[tid >> 6] = pv;
    __syncthreads();
    if (tid == 0) outp[(size_t)b * P_ + p] = prr[0] + prr[1] + prr[2] + prr[3] + out_b[0];
}

// ---------------------------------------------------------------- K5c: weight[b,p,i] = (1/(p+1)) * sum_k (U[k]@M)[i] * x[b,k,i]
__global__ __launch_bounds__(256) void k_wout(const float* __restrict__ ustore,
                                              const float* __restrict__ Mmat,
                                              const float* __restrict__ x,
                                              float* __restrict__ out) {
    int p = 62 - (blockIdx.x >> 5);
    int b = blockIdx.x & 31;
    int tid = threadIdx.x;
    __shared__ float Ut[E_][68];
    size_t tri = (size_t)p * (p + 1) / 2;
    for (int k = 0; k <= p; ++k)
        Ut[tid][k] = ustore[((tri + (size_t)k) * B_ + b) * (size_t)E_ + tid];
    __syncthreads();
    float gacc = 0.f;
    int nch = (p >> 4) + 1;
    const float* xb = x + (size_t)b * T_ * 256;
    for (int kc = 0; kc < nch; ++kc) {
        float acc[16];
        #pragma unroll
        for (int kk = 0; kk < 16; ++kk) acc[kk] = 0.f;
        for (int e = 0; e < 256; ++e) {
            float m = Mmat[(size_t)e * 256 + tid];
            const float4* up = reinterpret_cast<const float4*>(&Ut[e][kc * 16]);
            float4 u0 = up[0], u1 = up[1], u2 = up[2], u3 = up[3];
            acc[0]  += u0.x * m; acc[1]  += u0.y * m; acc[2]  += u0.z * m; acc[3]  += u0.w * m;
            acc[4]  += u1.x * m; acc[5]  += u1.y * m; acc[6]  += u1.z * m; acc[7]  += u1.w * m;
            acc[8]  += u2.x * m; acc[9]  += u2.y * m; acc[10] += u2.z * m; acc[11] += u2.w * m;
            acc[12] += u3.x * m; acc[13] += u3.y * m; acc[14] += u3.z * m; acc[15] += u3.w * m;
        }
        #pragma unroll
        for (int kk = 0; kk < 16; ++kk) {
            int k = kc * 16 + kk;
            if (k <= p) gacc += acc[kk] * xb[(size_t)k * 256 + tid];
        }
    }
    out[2016 + ((size_t)b * P_ + p) * 256 + tid] = gacc / (float)(p + 1);
}

// ---------------------------------------------------------------- host
extern "C" void kernel_launch(void* const* d_in, const int* in_sizes, int n_in,
                              void* d_out, int out_size, void* d_ws, size_t ws_size,
                              hipStream_t stream) {
    const float* x       = (const float*)d_in[0];
    const float* emb_w   = (const float*)d_in[1];
    const float* emb_b   = (const float*)d_in[2];
    const float* a_wih   = (const float*)d_in[3];
    const float* a_whh   = (const float*)d_in[4];
    const float* a_bih   = (const float*)d_in[5];
    const float* a_bhh   = (const float*)d_in[6];
    const float* b_wih   = (const float*)d_in[7];
    const float* b_whh   = (const float*)d_in[8];
    const float* b_bih   = (const float*)d_in[9];
    const float* b_bhh   = (const float*)d_in[10];
    const float* alpha_w = (const float*)d_in[11];
    const float* alpha_b = (const float*)d_in[12];
    const float* beta_w  = (const float*)d_in[13];
    const float* beta_b  = (const float*)d_in[14];
    const float* out_w   = (const float*)d_in[15];
    const float* out_b   = (const float*)d_in[16];
    float* out = (float*)d_out;

    float* ws = (float*)d_ws;
    // ws layout (floats), total 20,705,280 floats = 82.8 MB (same as R3)
    float* emb      = ws;                            // 524288
    _Float16* giTa  = (_Float16*)(emb + 524288);     // 768*2048 h = 786432 f
    _Float16* giTb  = giTa + 1572864;                // 786432 f
    _Float16* gpa   = giTb + 1572864;                // 786432 f
    _Float16* gpb   = gpa  + 1572864;                // 786432 f
    float* Mmat     = (float*)(gpb + 1572864);       // 65536
    float* pre      = Mmat  + 65536;                 // 129024
    float* alpha    = pre   + 129024;                // 129024
    _Float16* wfa   = (_Float16*)(alpha + 129024);   // 196608 h = 98304 f
    _Float16* wfb   = wfa + 196608;                  // 98304 f
    float* hstore   = (float*)(wfb + 196608);        // 16515072

    k_prep<<<256, 256, 0, stream>>>(emb_w, out_w, Mmat);
    k_emb<<<2048, 256, 0, stream>>>(x, emb_w, emb_b, emb);
    k_gates<<<256, 256, 0, stream>>>(emb, a_wih, a_bih, a_bhh, b_wih, b_bih, b_bhh, giTa, giTb);
    k_wfrag<<<384, 64, 0, stream>>>(a_whh, wfa);
    k_wfrag<<<384, 64, 0, stream>>>(b_whh, wfb);
    k_gipack<<<128, 512, 0, stream>>>(giTa, giTb, gpa, gpb);
    k_gru_f<<<126, 512, 0, stream>>>(gpa, gpb, wfa, wfb, a_bhh, b_bhh,
                                     alpha_w, alpha_b, pre, hstore);
    k_softmax<<<2016, 64, 0, stream>>>(pre, alpha);
    k_beta<<<2016, 256, 0, stream>>>(hstore, beta_w, beta_b, alpha, emb, out_w, out_b, out);
    k_wout<<<2016, 256, 0, stream>>>(hstore, Mmat, x, out);
}